// Round 18
// baseline (126.947 us; speedup 1.0000x reference)
//
#include <hip/hip_runtime.h>
#include <math.h>

#define BB 2
#define SS 2048
#define DD 1024
#define HH 16
#define M_TOTAL (BB*SS)   // 4096

typedef __attribute__((ext_vector_type(8))) short bf16x8;
typedef __attribute__((ext_vector_type(4))) float f32x4;

__device__ __forceinline__ short f2bf(float f) {
    union { float f; unsigned u; } v; v.f = f;
    unsigned r = v.u + 0x7fffu + ((v.u >> 16) & 1u);
    return (short)(r >> 16);
}
__device__ __forceinline__ float bf2f(short h) {
    union { unsigned u; float f; } v; v.u = ((unsigned)(unsigned short)h) << 16;
    return v.f;
}
__device__ __forceinline__ unsigned cvt_pk_bf16(float lo, float hi) {
    unsigned r;
    asm volatile("v_cvt_pk_bf16_f32 %0, %1, %2" : "=v"(r) : "v"(lo), "v"(hi));
    return r;
}
// async global->LDS, 16B per lane; LDS dest = wave-uniform base + lane*16
__device__ __forceinline__ void gload16(const void* g, void* l) {
    __builtin_amdgcn_global_load_lds(
        (const __attribute__((address_space(1))) unsigned int*)g,
        (__attribute__((address_space(3))) unsigned int*)l, 16, 0, 0);
}

// ---------------------------------------------------------------------------
// Fused fp32 -> bf16 conversion of all 5 tensors in one dispatch.
// ---------------------------------------------------------------------------
__global__ __launch_bounds__(256) void cvt_all(const float* __restrict__ x,
                                               const float* __restrict__ wq,
                                               const float* __restrict__ wk,
                                               const float* __restrict__ wv,
                                               const float* __restrict__ wo,
                                               short* __restrict__ xb,
                                               short* __restrict__ wqb,
                                               short* __restrict__ wkb,
                                               short* __restrict__ wvb,
                                               short* __restrict__ wob,
                                               float qscale)
{
    const size_t T = (size_t)M_TOTAL * DD;     // 4 M
    const size_t W = (size_t)DD * DD;          // 1 M
    size_t i = ((size_t)blockIdx.x * 256 + threadIdx.x) * 4;
    const float* src; short* dst; float sc = 1.0f; size_t off;
    if (i < T)              { src = x;  dst = xb;  off = i; }
    else if (i < T + W)     { src = wq; dst = wqb; off = i - T; sc = qscale; }
    else if (i < T + 2*W)   { src = wk; dst = wkb; off = i - T - W; }
    else if (i < T + 3*W)   { src = wv; dst = wvb; off = i - T - 2*W; }
    else                    { src = wo; dst = wob; off = i - T - 3*W; }
    float4 v = *(const float4*)(src + off);
    short4 o;
    o.x = f2bf(v.x * sc); o.y = f2bf(v.y * sc);
    o.z = f2bf(v.z * sc); o.w = f2bf(v.w * sc);
    *(short4*)(dst + off) = o;
}

// ---------------------------------------------------------------------------
// bf16 MFMA GEMM: C[M,N] = A[M,K] @ W[N,K]^T, 128xBN tile, BK=64, 4 waves.
// blockIdx.z selects among up to 3 (W, C) pairs (QKV fusion -> 3 blocks/CU).
// Grid transposed: blockIdx.x = n-tile (fastest) => XCD = bid%8 = n-panel.
// ---------------------------------------------------------------------------
template<int BN, int OUT_BF16>
__global__ __launch_bounds__(256) void gemm_nt_mfma(const short* __restrict__ A,
                                                    const short* __restrict__ W0,
                                                    const short* __restrict__ W1,
                                                    const short* __restrict__ W2,
                                                    void* __restrict__ C0,
                                                    void* __restrict__ C1,
                                                    void* __restrict__ C2,
                                                    int M, int N, int K)
{
    constexpr int WC = BN / 64;          // wave grid cols
    constexpr int WR = 4 / WC;           // wave grid rows
    constexpr int MW = 128 / WR;         // rows per wave (64 or 32)
    constexpr int MT = MW / 16;          // m-frags per wave (4 or 2)

    __shared__ __align__(16) short As[128 * 64];
    __shared__ __align__(16) short Bs[BN * 64];

    const short* W = (blockIdx.z == 0) ? W0 : (blockIdx.z == 1) ? W1 : W2;
    void* Cout     = (blockIdx.z == 0) ? C0 : (blockIdx.z == 1) ? C1 : C2;

    const int tid = threadIdx.x;
    const int lane = tid & 63;
    const int w = tid >> 6;
    const int lg = lane >> 4, lc = lane & 15;
    const int wr = w / WC, wc = w % WC;
    const int m0 = blockIdx.y * 128, n0 = blockIdx.x * BN;   // n fastest
    const int wbase = (tid & 0xC0) * 8;   // w*64 chunks * 8 shorts

    f32x4 acc[MT][4] = {};

    for (int k0 = 0; k0 < K; k0 += 64) {
        __syncthreads();   // WAR: previous tile's LDS reads complete
#pragma unroll
        for (int it = 0; it < 4; ++it) {
            int cl = it * 256 + tid;
            int r = cl >> 3;
            int c = (cl & 7) ^ (r & 7);            // inverse-swizzled source
            gload16(A + (size_t)(m0 + r) * K + k0 + c * 8, &As[it * 2048 + wbase]);
        }
#pragma unroll
        for (int it = 0; it < BN / 32; ++it) {
            int cl = it * 256 + tid;
            int r = cl >> 3;
            int c = (cl & 7) ^ (r & 7);
            gload16(W + (size_t)(n0 + r) * K + k0 + c * 8, &Bs[it * 2048 + wbase]);
        }
        __syncthreads();   // RAW: vmcnt(0) drained by compiler before barrier
#pragma unroll
        for (int ks = 0; ks < 2; ++ks) {
            bf16x8 af[MT], bfr[4];
#pragma unroll
            for (int mt = 0; mt < MT; ++mt) {
                int row = wr * MW + mt * 16 + lc;
                af[mt] = *(const bf16x8*)&As[row * 64 + (((ks * 4 + lg) ^ (row & 7)) * 8)];
            }
#pragma unroll
            for (int nt = 0; nt < 4; ++nt) {
                int row = wc * 64 + nt * 16 + lc;
                bfr[nt] = *(const bf16x8*)&Bs[row * 64 + (((ks * 4 + lg) ^ (row & 7)) * 8)];
            }
#pragma unroll
            for (int mt = 0; mt < MT; ++mt)
#pragma unroll
                for (int nt = 0; nt < 4; ++nt)
                    acc[mt][nt] = __builtin_amdgcn_mfma_f32_16x16x32_bf16(
                        af[mt], bfr[nt], acc[mt][nt], 0, 0, 0);
        }
    }
#pragma unroll
    for (int mt = 0; mt < MT; ++mt)
#pragma unroll
        for (int nt = 0; nt < 4; ++nt)
#pragma unroll
            for (int rg = 0; rg < 4; ++rg) {
                int row = m0 + wr * MW + mt * 16 + lg * 4 + rg;
                int col = n0 + wc * 64 + nt * 16 + lc;
                if (OUT_BF16)
                    ((short*)Cout)[(size_t)row * N + col] = f2bf(acc[mt][nt][rg]);
                else
                    ((float*)Cout)[(size_t)row * N + col] = acc[mt][nt][rg];
            }
}

// ---------------------------------------------------------------------------
// RoPE on bf16 Q,K in-place (Q pre-scaled; rope is linear so order is fine).
// ---------------------------------------------------------------------------
__global__ __launch_bounds__(256) void rope_qk(short* __restrict__ Q,
                                               short* __restrict__ K,
                                               const int* __restrict__ pos)
{
    const int t = blockIdx.x * 256 + threadIdx.x;
    const int ig = t & 7;
    const int h = (t >> 3) & 15;
    const int s = (t >> 7) & 2047;
    const int b = t >> 18;
    const float p = (float)pos[s];
    const size_t off = ((size_t)(b * SS + s)) * DD + h * 64 + ig * 8;
    bf16x8 q8 = *(bf16x8*)(Q + off);
    bf16x8 k8 = *(bf16x8*)(K + off);
#pragma unroll
    for (int j = 0; j < 4; ++j) {
        int i = ig * 4 + j;
        float ang = p * __expf(-(float)i * (9.210340371976184f / 32.0f));
        float c = cosf(ang), sn = sinf(ang);
        float q1 = bf2f(q8[2 * j]), q2 = bf2f(q8[2 * j + 1]);
        q8[2 * j]     = f2bf(q1 * c - q2 * sn);
        q8[2 * j + 1] = f2bf(q1 * sn + q2 * c);
        float k1 = bf2f(k8[2 * j]), k2 = bf2f(k8[2 * j + 1]);
        k8[2 * j]     = f2bf(k1 * c - k2 * sn);
        k8[2 * j + 1] = f2bf(k1 * sn + k2 * c);
    }
    *(bf16x8*)(Q + off) = q8;
    *(bf16x8*)(K + off) = k8;
}

// ---------------------------------------------------------------------------
// MFMA flash attention v9: TWO Q-GROUPS PER WAVE (32 q-rows/wave, QBLK=128,
// 4 waves). Every K/V fragment read from LDS feeds TWO MFMAs (one per
// q-group) => K-frag + V-frag LDS reads, staging, and barriers per q-row
// all halve vs R16. (v6's QBLK=128 with 8 waves kept 16 q/wave => null;
// the lever is q-rows PER WAVE.)
// Swapped QK^T, double-buffered K/V, one barrier/tile, fixed-m exp2
// softmax, deferred l-reduce, b64 P-writes via per-wave-per-group LDS.
// Group 0 = rows qt*128+w*16+lc, group 1 = +64. Group 0 is fully masked on
// the last key-tile (exp2 -> 0, correct; ~6% avg waste).
// bh in LOW 5 bits => same-head blocks 32 apart => same XCD L2.
// ---------------------------------------------------------------------------
__global__ __launch_bounds__(256) void attn_mfma(const short* __restrict__ Q,
                                                 const short* __restrict__ K,
                                                 const short* __restrict__ V,
                                                 short* __restrict__ O)
{
    __shared__ __align__(16) short Ks[2][64 * 64];         // [key][c], chunk^=(row&7)
    __shared__ __align__(16) unsigned Vt32[2][64 * 36];    // [ds][kp swz], padded
    __shared__ __align__(16) unsigned Pl32[4][2][16 * 36]; // per-wave per-group P^T

    const int tid = threadIdx.x;
    const int lane = tid & 63;
    const int w = tid >> 6;
    const int lg = lane >> 4, lc = lane & 15;

    const int bid = blockIdx.x;
    const int qt = 15 - (bid >> 5);      // 128-row q-tile, long blocks first
    const int bh = bid & 31;             // LOW bits: same-XCD per head
    const int b = bh >> 4, h = bh & 15;

    const short* Qh = Q + (size_t)b * SS * DD + h * 64;
    const short* Kh = K + (size_t)b * SS * DD + h * 64;
    const short* Vh = V + (size_t)b * SS * DD + h * 64;
    short* Oh = O + (size_t)b * SS * DD + h * 64;

    const int qg0 = qt * 128 + w * 16 + lc;   // group-0 q row
    const int qg1 = qg0 + 64;                 // group-1 q row
    bf16x8 qa[2][2];
#pragma unroll
    for (int ks = 0; ks < 2; ++ks) {
        qa[0][ks] = *(const bf16x8*)(Qh + (size_t)qg0 * DD + ks * 32 + lg * 8);
        qa[1][ks] = *(const bf16x8*)(Qh + (size_t)qg1 * DD + ks * 32 + lg * 8);
    }

    f32x4 oaccT[2][4] = {};
    float l0 = 0.0f, l1 = 0.0f;

    const int vc = tid & 7, vrp = tid >> 3;  // V staging: ds-chunk, key-pair
    unsigned* Pw0 = &Pl32[w][0][0];
    unsigned* Pw1 = &Pl32[w][1][0];
    const int kbase_lds = (tid & 0xC0) * 8;  // wave-uniform gload dest
    const int nkt = 2 * qt + 2;              // 64-key tiles this block

    // ---- prologue: stage tile 0 into buffer 0 ----
    {
        bf16x8 v0 = *(const bf16x8*)(Vh + (size_t)(2 * vrp) * DD + vc * 8);
        bf16x8 v1 = *(const bf16x8*)(Vh + (size_t)(2 * vrp + 1) * DD + vc * 8);
#pragma unroll
        for (int it = 0; it < 2; ++it) {
            int cl = it * 256 + tid;
            int r = cl >> 3;
            int c = (cl & 7) ^ (r & 7);
            gload16(Kh + (size_t)r * DD + c * 8, &Ks[0][it * 2048 + kbase_lds]);
        }
#pragma unroll
        for (int j = 0; j < 8; ++j) {
            int ds = vc * 8 + j;
            unsigned pk = (unsigned)(unsigned short)v0[j] |
                          ((unsigned)(unsigned short)v1[j] << 16);
            Vt32[0][ds * 36 + (vrp ^ (vc << 2))] = pk;
        }
    }
    __syncthreads();
    int cur = 0;

    for (int kt = 0; kt < nkt; ++kt) {
        // ---- stage tile kt+1 into buf^1 (issue early; write V late) ----
        bf16x8 v0n, v1n;
        const bool more = (kt + 1 < nkt);
        if (more) {
            const int nv0 = (kt + 1) * 64;
            v0n = *(const bf16x8*)(Vh + (size_t)(nv0 + 2 * vrp) * DD + vc * 8);
            v1n = *(const bf16x8*)(Vh + (size_t)(nv0 + 2 * vrp + 1) * DD + vc * 8);
#pragma unroll
            for (int it = 0; it < 2; ++it) {
                int cl = it * 256 + tid;
                int r = cl >> 3;
                int c = (cl & 7) ^ (r & 7);
                gload16(Kh + (size_t)(nv0 + r) * DD + c * 8,
                        &Ks[cur ^ 1][it * 2048 + kbase_lds]);
            }
        }

        // ---- QK^T swapped, both groups share each K fragment ----
        f32x4 s[2][4] = {};
        __builtin_amdgcn_s_setprio(1);
#pragma unroll
        for (int ks = 0; ks < 2; ++ks) {
            int c2 = ks * 4 + lg;
#pragma unroll
            for (int t = 0; t < 4; ++t) {
                int kr = t * 16 + lc;
                bf16x8 kb = *(const bf16x8*)&Ks[cur][kr * 64 + ((c2 ^ (kr & 7)) * 8)];
                s[0][t] = __builtin_amdgcn_mfma_f32_16x16x32_bf16(kb, qa[0][ks], s[0][t], 0, 0, 0);
                s[1][t] = __builtin_amdgcn_mfma_f32_16x16x32_bf16(kb, qa[1][ks], s[1][t], 0, 0, 0);
            }
        }
        __builtin_amdgcn_s_setprio(0);

        // ---- causal mask (last two key-tiles only) ----
        if (kt >= 2 * qt) {
            const int kv0 = kt * 64;
#pragma unroll
            for (int t = 0; t < 4; ++t)
#pragma unroll
                for (int rg = 0; rg < 4; ++rg) {
                    int key = kv0 + t * 16 + lg * 4 + rg;
                    if (key > qg0) s[0][t][rg] = -1e30f;
                    if (key > qg1) s[1][t][rg] = -1e30f;
                }
        }

        // ---- fixed-m softmax both groups: P = exp2(s) ----
#pragma unroll
        for (int t = 0; t < 4; ++t) {
            float a0 = exp2f(s[0][t][0]);
            float a1 = exp2f(s[0][t][1]);
            float a2 = exp2f(s[0][t][2]);
            float a3 = exp2f(s[0][t][3]);
            l0 += (a0 + a1) + (a2 + a3);
            uint2 pk0;
            pk0.x = cvt_pk_bf16(a0, a1);
            pk0.y = cvt_pk_bf16(a2, a3);
            *(uint2*)&Pw0[lc * 36 + 8 * t + 2 * lg] = pk0;
            float b0 = exp2f(s[1][t][0]);
            float b1 = exp2f(s[1][t][1]);
            float b2 = exp2f(s[1][t][2]);
            float b3 = exp2f(s[1][t][3]);
            l1 += (b0 + b1) + (b2 + b3);
            uint2 pk1;
            pk1.x = cvt_pk_bf16(b0, b1);
            pk1.y = cvt_pk_bf16(b2, b3);
            *(uint2*)&Pw1[lc * 36 + 8 * t + 2 * lg] = pk1;
        }

        // ---- PV: each V fragment feeds both groups ----
        __builtin_amdgcn_s_setprio(1);
#pragma unroll
        for (int ks = 0; ks < 2; ++ks) {
            bf16x8 pb0 = *(const bf16x8*)&Pw0[lc * 36 + 16 * ks + 4 * lg];
            bf16x8 pb1 = *(const bf16x8*)&Pw1[lc * 36 + 16 * ks + 4 * lg];
#pragma unroll
            for (int dt = 0; dt < 4; ++dt) {
                int vr = dt * 16 + lc;
                bf16x8 vb = *(const bf16x8*)&Vt32[cur][vr * 36 +
                                4 * ((ks * 4 + lg) ^ ((vr >> 3) & 7))];
                oaccT[0][dt] = __builtin_amdgcn_mfma_f32_16x16x32_bf16(vb, pb0, oaccT[0][dt], 0, 0, 0);
                oaccT[1][dt] = __builtin_amdgcn_mfma_f32_16x16x32_bf16(vb, pb1, oaccT[1][dt], 0, 0, 0);
            }
        }
        __builtin_amdgcn_s_setprio(0);

        // ---- late V write for tile kt+1 ----
        if (more) {
#pragma unroll
            for (int j = 0; j < 8; ++j) {
                int ds = vc * 8 + j;
                unsigned pk = (unsigned)(unsigned short)v0n[j] |
                              ((unsigned)(unsigned short)v1n[j] << 16);
                Vt32[cur ^ 1][ds * 36 + (vrp ^ (vc << 2))] = pk;
            }
        }
        __syncthreads();   // single barrier per tile
        cur ^= 1;
    }

    // ---- epilogue: finish l per group, write O ----
    l0 += __shfl_xor(l0, 16);
    l0 += __shfl_xor(l0, 32);
    l1 += __shfl_xor(l1, 16);
    l1 += __shfl_xor(l1, 32);
    const float inv0 = 1.0f / l0;
    const float inv1 = 1.0f / l1;
#pragma unroll
    for (int dt = 0; dt < 4; ++dt)
#pragma unroll
        for (int rg = 0; rg < 4; ++rg) {
            Oh[(size_t)qg0 * DD + dt * 16 + lg * 4 + rg] = f2bf(oaccT[0][dt][rg] * inv0);
            Oh[(size_t)qg1 * DD + dt * 16 + lg * 4 + rg] = f2bf(oaccT[1][dt][rg] * inv1);
        }
}

// ---------------------------------------------------------------------------
extern "C" void kernel_launch(void* const* d_in, const int* in_sizes, int n_in,
                              void* d_out, int out_size, void* d_ws, size_t ws_size,
                              hipStream_t stream)
{
    const float* x   = (const float*)d_in[0];
    const int*   pos = (const int*)d_in[1];
    const float* Wq  = (const float*)d_in[2];
    const float* Wk  = (const float*)d_in[3];
    const float* Wv  = (const float*)d_in[4];
    const float* Wo  = (const float*)d_in[5];
    float* out = (float*)d_out;

    const size_t T = (size_t)M_TOTAL * DD;
    const size_t WSZ = (size_t)DD * DD;
    short* xb  = (short*)d_ws;
    short* wqb = xb + T;
    short* wkb = wqb + WSZ;
    short* wvb = wkb + WSZ;
    short* wob = wvb + WSZ;
    short* Qb  = wob + WSZ;
    short* Kb  = Qb + T;
    short* Vb  = Kb + T;
    short* AOb = Vb + T;

    // One fused cvt dispatch; Wq pre-scaled by 0.125*log2(e) (exp2 domain).
    const int cvt_blocks = (int)((T + 4 * WSZ) / 1024);
    cvt_all<<<cvt_blocks, 256, 0, stream>>>(x, Wq, Wk, Wv, Wo,
                                            xb, wqb, wkb, wvb, wob,
                                            0.18033688011112042f);

    // QKV fused, n-fastest grid: XCD = bid%8 = n-panel -> W pinned per-XCD L2
    dim3 gqkv(DD / 128, M_TOTAL / 128, 3);
    gemm_nt_mfma<128, 1><<<gqkv, 256, 0, stream>>>(
        xb, wqb, wkb, wvb, Qb, Kb, Vb, M_TOTAL, DD, DD);

    rope_qk<<<(BB * SS * HH * 8) / 256, 256, 0, stream>>>(Qb, Kb, pos);

    // Attention: 512 blocks (128-row q-tiles), bh low bits, long-first
    attn_mfma<<<BB * HH * (SS / 128), 256, 0, stream>>>(Qb, Kb, Vb, AOb);

    // Output projection, n-fastest grid: 512 blocks = 2 blocks/CU
    dim3 go(DD / 64, M_TOTAL / 128, 1);
    gemm_nt_mfma<64, 0><<<go, 256, 0, stream>>>(
        AOb, wob, wob, wob, (void*)out, (void*)out, (void*)out, M_TOTAL, DD, DD);
}

// Round 22
// 113.409 us; speedup vs baseline: 1.1194x; 1.1194x over previous
//
#include <hip/hip_runtime.h>
#include <math.h>

#define BB 2
#define SS 2048
#define DD 1024
#define HH 16
#define M_TOTAL (BB*SS)   // 4096

typedef __attribute__((ext_vector_type(8))) short bf16x8;
typedef __attribute__((ext_vector_type(4))) float f32x4;

__device__ __forceinline__ short f2bf(float f) {
    union { float f; unsigned u; } v; v.f = f;
    unsigned r = v.u + 0x7fffu + ((v.u >> 16) & 1u);
    return (short)(r >> 16);
}
__device__ __forceinline__ float bf2f(short h) {
    union { unsigned u; float f; } v; v.u = ((unsigned)(unsigned short)h) << 16;
    return v.f;
}
__device__ __forceinline__ unsigned cvt_pk_bf16(float lo, float hi) {
    unsigned r;
    asm volatile("v_cvt_pk_bf16_f32 %0, %1, %2" : "=v"(r) : "v"(lo), "v"(hi));
    return r;
}
// async global->LDS, 16B per lane; LDS dest = wave-uniform base + lane*16
__device__ __forceinline__ void gload16(const void* g, void* l) {
    __builtin_amdgcn_global_load_lds(
        (const __attribute__((address_space(1))) unsigned int*)g,
        (__attribute__((address_space(3))) unsigned int*)l, 16, 0, 0);
}

// ---------------------------------------------------------------------------
// Fused fp32 -> bf16 conversion of all 5 tensors in one dispatch.
// ---------------------------------------------------------------------------
__global__ __launch_bounds__(256) void cvt_all(const float* __restrict__ x,
                                               const float* __restrict__ wq,
                                               const float* __restrict__ wk,
                                               const float* __restrict__ wv,
                                               const float* __restrict__ wo,
                                               short* __restrict__ xb,
                                               short* __restrict__ wqb,
                                               short* __restrict__ wkb,
                                               short* __restrict__ wvb,
                                               short* __restrict__ wob,
                                               float qscale)
{
    const size_t T = (size_t)M_TOTAL * DD;     // 4 M
    const size_t W = (size_t)DD * DD;          // 1 M
    size_t i = ((size_t)blockIdx.x * 256 + threadIdx.x) * 4;
    const float* src; short* dst; float sc = 1.0f; size_t off;
    if (i < T)              { src = x;  dst = xb;  off = i; }
    else if (i < T + W)     { src = wq; dst = wqb; off = i - T; sc = qscale; }
    else if (i < T + 2*W)   { src = wk; dst = wkb; off = i - T - W; }
    else if (i < T + 3*W)   { src = wv; dst = wvb; off = i - T - 2*W; }
    else                    { src = wo; dst = wob; off = i - T - 3*W; }
    float4 v = *(const float4*)(src + off);
    short4 o;
    o.x = f2bf(v.x * sc); o.y = f2bf(v.y * sc);
    o.z = f2bf(v.z * sc); o.w = f2bf(v.w * sc);
    *(short4*)(dst + off) = o;
}

// ---------------------------------------------------------------------------
// bf16 MFMA GEMM: C[M,N] = A[M,K] @ W[N,K]^T, 128xBN tile, BK=64, 4 waves.
// blockIdx.z selects among up to 3 (W, C) pairs (QKV fusion -> 3 blocks/CU).
// Grid transposed: blockIdx.x = n-tile (fastest) => XCD = bid%8 = n-panel.
// ---------------------------------------------------------------------------
template<int BN, int OUT_BF16>
__global__ __launch_bounds__(256) void gemm_nt_mfma(const short* __restrict__ A,
                                                    const short* __restrict__ W0,
                                                    const short* __restrict__ W1,
                                                    const short* __restrict__ W2,
                                                    void* __restrict__ C0,
                                                    void* __restrict__ C1,
                                                    void* __restrict__ C2,
                                                    int M, int N, int K)
{
    constexpr int WC = BN / 64;          // wave grid cols
    constexpr int WR = 4 / WC;           // wave grid rows
    constexpr int MW = 128 / WR;         // rows per wave (64 or 32)
    constexpr int MT = MW / 16;          // m-frags per wave (4 or 2)

    __shared__ __align__(16) short As[128 * 64];
    __shared__ __align__(16) short Bs[BN * 64];

    const short* W = (blockIdx.z == 0) ? W0 : (blockIdx.z == 1) ? W1 : W2;
    void* Cout     = (blockIdx.z == 0) ? C0 : (blockIdx.z == 1) ? C1 : C2;

    const int tid = threadIdx.x;
    const int lane = tid & 63;
    const int w = tid >> 6;
    const int lg = lane >> 4, lc = lane & 15;
    const int wr = w / WC, wc = w % WC;
    const int m0 = blockIdx.y * 128, n0 = blockIdx.x * BN;   // n fastest
    const int wbase = (tid & 0xC0) * 8;   // w*64 chunks * 8 shorts

    f32x4 acc[MT][4] = {};

    for (int k0 = 0; k0 < K; k0 += 64) {
        __syncthreads();   // WAR: previous tile's LDS reads complete
#pragma unroll
        for (int it = 0; it < 4; ++it) {
            int cl = it * 256 + tid;
            int r = cl >> 3;
            int c = (cl & 7) ^ (r & 7);            // inverse-swizzled source
            gload16(A + (size_t)(m0 + r) * K + k0 + c * 8, &As[it * 2048 + wbase]);
        }
#pragma unroll
        for (int it = 0; it < BN / 32; ++it) {
            int cl = it * 256 + tid;
            int r = cl >> 3;
            int c = (cl & 7) ^ (r & 7);
            gload16(W + (size_t)(n0 + r) * K + k0 + c * 8, &Bs[it * 2048 + wbase]);
        }
        __syncthreads();   // RAW: vmcnt(0) drained by compiler before barrier
#pragma unroll
        for (int ks = 0; ks < 2; ++ks) {
            bf16x8 af[MT], bfr[4];
#pragma unroll
            for (int mt = 0; mt < MT; ++mt) {
                int row = wr * MW + mt * 16 + lc;
                af[mt] = *(const bf16x8*)&As[row * 64 + (((ks * 4 + lg) ^ (row & 7)) * 8)];
            }
#pragma unroll
            for (int nt = 0; nt < 4; ++nt) {
                int row = wc * 64 + nt * 16 + lc;
                bfr[nt] = *(const bf16x8*)&Bs[row * 64 + (((ks * 4 + lg) ^ (row & 7)) * 8)];
            }
#pragma unroll
            for (int mt = 0; mt < MT; ++mt)
#pragma unroll
                for (int nt = 0; nt < 4; ++nt)
                    acc[mt][nt] = __builtin_amdgcn_mfma_f32_16x16x32_bf16(
                        af[mt], bfr[nt], acc[mt][nt], 0, 0, 0);
        }
    }
#pragma unroll
    for (int mt = 0; mt < MT; ++mt)
#pragma unroll
        for (int nt = 0; nt < 4; ++nt)
#pragma unroll
            for (int rg = 0; rg < 4; ++rg) {
                int row = m0 + wr * MW + mt * 16 + lg * 4 + rg;
                int col = n0 + wc * 64 + nt * 16 + lc;
                if (OUT_BF16)
                    ((short*)Cout)[(size_t)row * N + col] = f2bf(acc[mt][nt][rg]);
                else
                    ((float*)Cout)[(size_t)row * N + col] = acc[mt][nt][rg];
            }
}

// ---------------------------------------------------------------------------
// RoPE on bf16 Q,K in-place (Q pre-scaled; rope is linear so order is fine).
// ---------------------------------------------------------------------------
__global__ __launch_bounds__(256) void rope_qk(short* __restrict__ Q,
                                               short* __restrict__ K,
                                               const int* __restrict__ pos)
{
    const int t = blockIdx.x * 256 + threadIdx.x;
    const int ig = t & 7;
    const int h = (t >> 3) & 15;
    const int s = (t >> 7) & 2047;
    const int b = t >> 18;
    const float p = (float)pos[s];
    const size_t off = ((size_t)(b * SS + s)) * DD + h * 64 + ig * 8;
    bf16x8 q8 = *(bf16x8*)(Q + off);
    bf16x8 k8 = *(bf16x8*)(K + off);
#pragma unroll
    for (int j = 0; j < 4; ++j) {
        int i = ig * 4 + j;
        float ang = p * __expf(-(float)i * (9.210340371976184f / 32.0f));
        float c = cosf(ang), sn = sinf(ang);
        float q1 = bf2f(q8[2 * j]), q2 = bf2f(q8[2 * j + 1]);
        q8[2 * j]     = f2bf(q1 * c - q2 * sn);
        q8[2 * j + 1] = f2bf(q1 * sn + q2 * c);
        float k1 = bf2f(k8[2 * j]), k2 = bf2f(k8[2 * j + 1]);
        k8[2 * j]     = f2bf(k1 * c - k2 * sn);
        k8[2 * j + 1] = f2bf(k1 * sn + k2 * c);
    }
    *(bf16x8*)(Q + off) = q8;
    *(bf16x8*)(K + off) = k8;
}

// ---------------------------------------------------------------------------
// MFMA flash attention (measured-best structure, 47.2 us): swapped QK^T,
// double-buffered K/V, one barrier per K-tile, fixed-m exp2 softmax
// (overflow needs s > 127 = 88 sigma), deferred cross-lane l-reduce.
// qt = 31-(bid>>5) (long blocks first); bh in LOW 5 bits => same-head
// blocks 32 apart => same XCD L2. P-writes b64 (conflict-floor).
// Structural probes that REGRESSED vs this shape (kept for the record):
// QBLK=128/8-wave (R13), rope-in-attn (R15), shfl-routed P (R17),
// two-q-groups/wave (R18), causal pairing (R12 ~null).
// ---------------------------------------------------------------------------
__global__ __launch_bounds__(256) void attn_mfma(const short* __restrict__ Q,
                                                 const short* __restrict__ K,
                                                 const short* __restrict__ V,
                                                 short* __restrict__ O)
{
    __shared__ __align__(16) short Ks[2][64 * 64];         // [key][c], chunk^=(row&7)
    __shared__ __align__(16) unsigned Vt32[2][64 * 36];    // [ds][kp swz], padded
    __shared__ __align__(16) unsigned Pl32[4][16 * 36];    // per-wave P^T, padded

    const int tid = threadIdx.x;
    const int lane = tid & 63;
    const int w = tid >> 6;
    const int lg = lane >> 4, lc = lane & 15;

    const int bid = blockIdx.x;
    const int qt = 31 - (bid >> 5);      // long blocks first
    const int bh = bid & 31;             // LOW bits: same-XCD per head
    const int b = bh >> 4, h = bh & 15;

    const short* Qh = Q + (size_t)b * SS * DD + h * 64;
    const short* Kh = K + (size_t)b * SS * DD + h * 64;
    const short* Vh = V + (size_t)b * SS * DD + h * 64;
    short* Oh = O + (size_t)b * SS * DD + h * 64;

    const int qg = qt * 64 + w * 16 + lc;    // this lane's q row (global)
    bf16x8 qa[2];
#pragma unroll
    for (int ks = 0; ks < 2; ++ks)
        qa[ks] = *(const bf16x8*)(Qh + (size_t)qg * DD + ks * 32 + lg * 8);

    f32x4 oaccT[4] = {};
    float l = 0.0f;                          // per-lane partial row-sum

    const int vc = tid & 7, vrp = tid >> 3;  // V staging: ds-chunk, key-pair
    unsigned* Pw = &Pl32[w][0];
    const int kbase_lds = (tid & 0xC0) * 8;  // wave-uniform gload dest

    // ---- prologue: stage tile 0 into buffer 0 ----
    {
        bf16x8 v0 = *(const bf16x8*)(Vh + (size_t)(2 * vrp) * DD + vc * 8);
        bf16x8 v1 = *(const bf16x8*)(Vh + (size_t)(2 * vrp + 1) * DD + vc * 8);
#pragma unroll
        for (int it = 0; it < 2; ++it) {
            int cl = it * 256 + tid;
            int r = cl >> 3;
            int c = (cl & 7) ^ (r & 7);
            gload16(Kh + (size_t)r * DD + c * 8, &Ks[0][it * 2048 + kbase_lds]);
        }
#pragma unroll
        for (int j = 0; j < 8; ++j) {
            int ds = vc * 8 + j;
            unsigned pk = (unsigned)(unsigned short)v0[j] |
                          ((unsigned)(unsigned short)v1[j] << 16);
            Vt32[0][ds * 36 + (vrp ^ (vc << 2))] = pk;
        }
    }
    __syncthreads();
    int cur = 0;

    for (int kt = 0; kt <= qt; ++kt) {
        // ---- stage tile kt+1 into buf^1 (issue early; write V late) ----
        bf16x8 v0n, v1n;
        const bool more = (kt < qt);
        if (more) {
            const int nv0 = (kt + 1) * 64;
            v0n = *(const bf16x8*)(Vh + (size_t)(nv0 + 2 * vrp) * DD + vc * 8);
            v1n = *(const bf16x8*)(Vh + (size_t)(nv0 + 2 * vrp + 1) * DD + vc * 8);
#pragma unroll
            for (int it = 0; it < 2; ++it) {
                int cl = it * 256 + tid;
                int r = cl >> 3;
                int c = (cl & 7) ^ (r & 7);
                gload16(Kh + (size_t)(nv0 + r) * DD + c * 8,
                        &Ks[cur ^ 1][it * 2048 + kbase_lds]);
            }
        }

        // ---- QK^T swapped: s[t] = S^T[key = kv0+t*16+lg*4+rg][q=lc] ----
        f32x4 s[4] = {};
        __builtin_amdgcn_s_setprio(1);
#pragma unroll
        for (int ks = 0; ks < 2; ++ks) {
            int c2 = ks * 4 + lg;
#pragma unroll
            for (int t = 0; t < 4; ++t) {
                int kr = t * 16 + lc;
                bf16x8 kb = *(const bf16x8*)&Ks[cur][kr * 64 + ((c2 ^ (kr & 7)) * 8)];
                s[t] = __builtin_amdgcn_mfma_f32_16x16x32_bf16(kb, qa[ks], s[t], 0, 0, 0);
            }
        }
        __builtin_amdgcn_s_setprio(0);

        // ---- causal mask (diag tile only) ----
        if (kt == qt) {
            const int kv0 = kt * 64;
#pragma unroll
            for (int t = 0; t < 4; ++t)
#pragma unroll
                for (int rg = 0; rg < 4; ++rg)
                    if (kv0 + t * 16 + lg * 4 + rg > qg) s[t][rg] = -1e30f;
        }

        // ---- fixed-m softmax: P = exp2(s); per-lane partial sum ----
#pragma unroll
        for (int t = 0; t < 4; ++t) {
            float p0 = exp2f(s[t][0]);
            float p1 = exp2f(s[t][1]);
            float p2 = exp2f(s[t][2]);
            float p3 = exp2f(s[t][3]);
            l += (p0 + p1) + (p2 + p3);
            uint2 pk;
            pk.x = cvt_pk_bf16(p0, p1);
            pk.y = cvt_pk_bf16(p2, p3);
            *(uint2*)&Pw[lc * 36 + 8 * t + 2 * lg] = pk;
        }

        // ---- PV: O^T[d][q] += V^T[d][k] * P^T[k][q] ----
        __builtin_amdgcn_s_setprio(1);
#pragma unroll
        for (int ks = 0; ks < 2; ++ks) {
            bf16x8 pb = *(const bf16x8*)&Pw[lc * 36 + 16 * ks + 4 * lg];
#pragma unroll
            for (int dt = 0; dt < 4; ++dt) {
                int vr = dt * 16 + lc;
                bf16x8 vb = *(const bf16x8*)&Vt32[cur][vr * 36 +
                                4 * ((ks * 4 + lg) ^ ((vr >> 3) & 7))];
                oaccT[dt] = __builtin_amdgcn_mfma_f32_16x16x32_bf16(vb, pb, oaccT[dt], 0, 0, 0);
            }
        }
        __builtin_amdgcn_s_setprio(0);

        // ---- late V write for tile kt+1 ----
        if (more) {
#pragma unroll
            for (int j = 0; j < 8; ++j) {
                int ds = vc * 8 + j;
                unsigned pk = (unsigned)(unsigned short)v0n[j] |
                              ((unsigned)(unsigned short)v1n[j] << 16);
                Vt32[cur ^ 1][ds * 36 + (vrp ^ (vc << 2))] = pk;
            }
        }
        __syncthreads();   // single barrier per tile
        cur ^= 1;
    }

    // ---- epilogue: finish l across lane groups, write O ----
    l += __shfl_xor(l, 16);
    l += __shfl_xor(l, 32);
    const float inv = 1.0f / l;
#pragma unroll
    for (int dt = 0; dt < 4; ++dt)
#pragma unroll
        for (int rg = 0; rg < 4; ++rg)
            Oh[(size_t)qg * DD + dt * 16 + lg * 4 + rg] = f2bf(oaccT[dt][rg] * inv);
}

// ---------------------------------------------------------------------------
extern "C" void kernel_launch(void* const* d_in, const int* in_sizes, int n_in,
                              void* d_out, int out_size, void* d_ws, size_t ws_size,
                              hipStream_t stream)
{
    const float* x   = (const float*)d_in[0];
    const int*   pos = (const int*)d_in[1];
    const float* Wq  = (const float*)d_in[2];
    const float* Wk  = (const float*)d_in[3];
    const float* Wv  = (const float*)d_in[4];
    const float* Wo  = (const float*)d_in[5];
    float* out = (float*)d_out;

    const size_t T = (size_t)M_TOTAL * DD;
    const size_t WSZ = (size_t)DD * DD;
    short* xb  = (short*)d_ws;
    short* wqb = xb + T;
    short* wkb = wqb + WSZ;
    short* wvb = wkb + WSZ;
    short* wob = wvb + WSZ;
    short* Qb  = wob + WSZ;
    short* Kb  = Qb + T;
    short* Vb  = Kb + T;
    short* AOb = Vb + T;

    // One fused cvt dispatch; Wq pre-scaled by 0.125*log2(e) (exp2 domain).
    const int cvt_blocks = (int)((T + 4 * WSZ) / 1024);
    cvt_all<<<cvt_blocks, 256, 0, stream>>>(x, Wq, Wk, Wv, Wo,
                                            xb, wqb, wkb, wvb, wob,
                                            0.18033688011112042f);

    // QKV fused, n-fastest grid: XCD = bid%8 = n-panel -> W pinned per-XCD L2
    dim3 gqkv(DD / 128, M_TOTAL / 128, 3);
    gemm_nt_mfma<128, 1><<<gqkv, 256, 0, stream>>>(
        xb, wqb, wkb, wvb, Qb, Kb, Vb, M_TOTAL, DD, DD);

    rope_qk<<<(BB * SS * HH * 8) / 256, 256, 0, stream>>>(Qb, Kb, pos);

    // Attention: 1024 blocks, bh in low bits (XCD local), long blocks first
    attn_mfma<<<BB * HH * (SS / 64), 256, 0, stream>>>(Qb, Kb, Vb, AOb);

    // Output projection, n-fastest grid: 512 blocks = 2 blocks/CU
    dim3 go(DD / 64, M_TOTAL / 128, 1);
    gemm_nt_mfma<64, 0><<<go, 256, 0, stream>>>(
        AOb, wob, wob, wob, (void*)out, (void*)out, (void*)out, M_TOTAL, DD, DD);
}

// Round 23
// 112.462 us; speedup vs baseline: 1.1288x; 1.0084x over previous
//
#include <hip/hip_runtime.h>
#include <math.h>

#define BB 2
#define SS 2048
#define DD 1024
#define HH 16
#define M_TOTAL (BB*SS)   // 4096

typedef __attribute__((ext_vector_type(8))) short bf16x8;
typedef __attribute__((ext_vector_type(4))) float f32x4;

__device__ __forceinline__ short f2bf(float f) {
    union { float f; unsigned u; } v; v.f = f;
    unsigned r = v.u + 0x7fffu + ((v.u >> 16) & 1u);
    return (short)(r >> 16);
}
__device__ __forceinline__ float bf2f(short h) {
    union { unsigned u; float f; } v; v.u = ((unsigned)(unsigned short)h) << 16;
    return v.f;
}
__device__ __forceinline__ unsigned cvt_pk_bf16(float lo, float hi) {
    unsigned r;
    asm volatile("v_cvt_pk_bf16_f32 %0, %1, %2" : "=v"(r) : "v"(lo), "v"(hi));
    return r;
}
// async global->LDS, 16B per lane; LDS dest = wave-uniform base + lane*16
__device__ __forceinline__ void gload16(const void* g, void* l) {
    __builtin_amdgcn_global_load_lds(
        (const __attribute__((address_space(1))) unsigned int*)g,
        (__attribute__((address_space(3))) unsigned int*)l, 16, 0, 0);
}

// ---------------------------------------------------------------------------
// Fused fp32 -> bf16 conversion of all 5 tensors in one dispatch.
// 8 elems/thread: 2x float4 loads (32 B/lane) + one 16 B short8-equiv store.
// Segment boundaries are multiples of 2048 elems => block-aligned, no
// intra-block divergence.
// ---------------------------------------------------------------------------
__global__ __launch_bounds__(256) void cvt_all(const float* __restrict__ x,
                                               const float* __restrict__ wq,
                                               const float* __restrict__ wk,
                                               const float* __restrict__ wv,
                                               const float* __restrict__ wo,
                                               short* __restrict__ xb,
                                               short* __restrict__ wqb,
                                               short* __restrict__ wkb,
                                               short* __restrict__ wvb,
                                               short* __restrict__ wob,
                                               float qscale)
{
    const size_t T = (size_t)M_TOTAL * DD;     // 4 M
    const size_t W = (size_t)DD * DD;          // 1 M
    size_t i = ((size_t)blockIdx.x * 256 + threadIdx.x) * 8;
    const float* src; short* dst; float sc = 1.0f; size_t off;
    if (i < T)              { src = x;  dst = xb;  off = i; }
    else if (i < T + W)     { src = wq; dst = wqb; off = i - T; sc = qscale; }
    else if (i < T + 2*W)   { src = wk; dst = wkb; off = i - T - W; }
    else if (i < T + 3*W)   { src = wv; dst = wvb; off = i - T - 2*W; }
    else                    { src = wo; dst = wob; off = i - T - 3*W; }
    float4 v0 = *(const float4*)(src + off);
    float4 v1 = *(const float4*)(src + off + 4);
    bf16x8 o;
    o[0] = f2bf(v0.x * sc); o[1] = f2bf(v0.y * sc);
    o[2] = f2bf(v0.z * sc); o[3] = f2bf(v0.w * sc);
    o[4] = f2bf(v1.x * sc); o[5] = f2bf(v1.y * sc);
    o[6] = f2bf(v1.z * sc); o[7] = f2bf(v1.w * sc);
    *(bf16x8*)(dst + off) = o;
}

// ---------------------------------------------------------------------------
// bf16 MFMA GEMM: C[M,N] = A[M,K] @ W[N,K]^T, 128xBN tile, BK=64, 4 waves.
// blockIdx.z selects among up to 3 (W, C) pairs (QKV fusion -> 3 blocks/CU).
// Grid transposed: blockIdx.x = n-tile (fastest) => XCD = bid%8 = n-panel.
// ---------------------------------------------------------------------------
template<int BN, int OUT_BF16>
__global__ __launch_bounds__(256) void gemm_nt_mfma(const short* __restrict__ A,
                                                    const short* __restrict__ W0,
                                                    const short* __restrict__ W1,
                                                    const short* __restrict__ W2,
                                                    void* __restrict__ C0,
                                                    void* __restrict__ C1,
                                                    void* __restrict__ C2,
                                                    int M, int N, int K)
{
    constexpr int WC = BN / 64;          // wave grid cols
    constexpr int WR = 4 / WC;           // wave grid rows
    constexpr int MW = 128 / WR;         // rows per wave (64 or 32)
    constexpr int MT = MW / 16;          // m-frags per wave (4 or 2)

    __shared__ __align__(16) short As[128 * 64];
    __shared__ __align__(16) short Bs[BN * 64];

    const short* W = (blockIdx.z == 0) ? W0 : (blockIdx.z == 1) ? W1 : W2;
    void* Cout     = (blockIdx.z == 0) ? C0 : (blockIdx.z == 1) ? C1 : C2;

    const int tid = threadIdx.x;
    const int lane = tid & 63;
    const int w = tid >> 6;
    const int lg = lane >> 4, lc = lane & 15;
    const int wr = w / WC, wc = w % WC;
    const int m0 = blockIdx.y * 128, n0 = blockIdx.x * BN;   // n fastest
    const int wbase = (tid & 0xC0) * 8;   // w*64 chunks * 8 shorts

    f32x4 acc[MT][4] = {};

    for (int k0 = 0; k0 < K; k0 += 64) {
        __syncthreads();   // WAR: previous tile's LDS reads complete
#pragma unroll
        for (int it = 0; it < 4; ++it) {
            int cl = it * 256 + tid;
            int r = cl >> 3;
            int c = (cl & 7) ^ (r & 7);            // inverse-swizzled source
            gload16(A + (size_t)(m0 + r) * K + k0 + c * 8, &As[it * 2048 + wbase]);
        }
#pragma unroll
        for (int it = 0; it < BN / 32; ++it) {
            int cl = it * 256 + tid;
            int r = cl >> 3;
            int c = (cl & 7) ^ (r & 7);
            gload16(W + (size_t)(n0 + r) * K + k0 + c * 8, &Bs[it * 2048 + wbase]);
        }
        __syncthreads();   // RAW: vmcnt(0) drained by compiler before barrier
#pragma unroll
        for (int ks = 0; ks < 2; ++ks) {
            bf16x8 af[MT], bfr[4];
#pragma unroll
            for (int mt = 0; mt < MT; ++mt) {
                int row = wr * MW + mt * 16 + lc;
                af[mt] = *(const bf16x8*)&As[row * 64 + (((ks * 4 + lg) ^ (row & 7)) * 8)];
            }
#pragma unroll
            for (int nt = 0; nt < 4; ++nt) {
                int row = wc * 64 + nt * 16 + lc;
                bfr[nt] = *(const bf16x8*)&Bs[row * 64 + (((ks * 4 + lg) ^ (row & 7)) * 8)];
            }
#pragma unroll
            for (int mt = 0; mt < MT; ++mt)
#pragma unroll
                for (int nt = 0; nt < 4; ++nt)
                    acc[mt][nt] = __builtin_amdgcn_mfma_f32_16x16x32_bf16(
                        af[mt], bfr[nt], acc[mt][nt], 0, 0, 0);
        }
    }
#pragma unroll
    for (int mt = 0; mt < MT; ++mt)
#pragma unroll
        for (int nt = 0; nt < 4; ++nt)
#pragma unroll
            for (int rg = 0; rg < 4; ++rg) {
                int row = m0 + wr * MW + mt * 16 + lg * 4 + rg;
                int col = n0 + wc * 64 + nt * 16 + lc;
                if (OUT_BF16)
                    ((short*)Cout)[(size_t)row * N + col] = f2bf(acc[mt][nt][rg]);
                else
                    ((float*)Cout)[(size_t)row * N + col] = acc[mt][nt][rg];
            }
}

// ---------------------------------------------------------------------------
// RoPE on bf16 Q,K in-place (Q pre-scaled; rope is linear so order is fine).
// ---------------------------------------------------------------------------
__global__ __launch_bounds__(256) void rope_qk(short* __restrict__ Q,
                                               short* __restrict__ K,
                                               const int* __restrict__ pos)
{
    const int t = blockIdx.x * 256 + threadIdx.x;
    const int ig = t & 7;
    const int h = (t >> 3) & 15;
    const int s = (t >> 7) & 2047;
    const int b = t >> 18;
    const float p = (float)pos[s];
    const size_t off = ((size_t)(b * SS + s)) * DD + h * 64 + ig * 8;
    bf16x8 q8 = *(bf16x8*)(Q + off);
    bf16x8 k8 = *(bf16x8*)(K + off);
#pragma unroll
    for (int j = 0; j < 4; ++j) {
        int i = ig * 4 + j;
        float ang = p * __expf(-(float)i * (9.210340371976184f / 32.0f));
        float c = cosf(ang), sn = sinf(ang);
        float q1 = bf2f(q8[2 * j]), q2 = bf2f(q8[2 * j + 1]);
        q8[2 * j]     = f2bf(q1 * c - q2 * sn);
        q8[2 * j + 1] = f2bf(q1 * sn + q2 * c);
        float k1 = bf2f(k8[2 * j]), k2 = bf2f(k8[2 * j + 1]);
        k8[2 * j]     = f2bf(k1 * c - k2 * sn);
        k8[2 * j + 1] = f2bf(k1 * sn + k2 * c);
    }
    *(bf16x8*)(Q + off) = q8;
    *(bf16x8*)(K + off) = k8;
}

// ---------------------------------------------------------------------------
// MFMA flash attention (measured-best structure, 47.2 us): swapped QK^T,
// double-buffered K/V, one barrier per K-tile, fixed-m exp2 softmax
// (overflow needs s > 127 = 88 sigma), deferred cross-lane l-reduce.
// qt = 31-(bid>>5) (long blocks first); bh in LOW 5 bits => same-head
// blocks 32 apart => same XCD L2. P-writes b64 (conflict-floor).
// Structural probes that REGRESSED vs this shape (kept for the record):
// QBLK=128/8-wave (R13), rope-in-attn (R15), shfl-routed P (R17),
// two-q-groups/wave (R18), causal pairing (R12 ~null).
// ---------------------------------------------------------------------------
__global__ __launch_bounds__(256) void attn_mfma(const short* __restrict__ Q,
                                                 const short* __restrict__ K,
                                                 const short* __restrict__ V,
                                                 short* __restrict__ O)
{
    __shared__ __align__(16) short Ks[2][64 * 64];         // [key][c], chunk^=(row&7)
    __shared__ __align__(16) unsigned Vt32[2][64 * 36];    // [ds][kp swz], padded
    __shared__ __align__(16) unsigned Pl32[4][16 * 36];    // per-wave P^T, padded

    const int tid = threadIdx.x;
    const int lane = tid & 63;
    const int w = tid >> 6;
    const int lg = lane >> 4, lc = lane & 15;

    const int bid = blockIdx.x;
    const int qt = 31 - (bid >> 5);      // long blocks first
    const int bh = bid & 31;             // LOW bits: same-XCD per head
    const int b = bh >> 4, h = bh & 15;

    const short* Qh = Q + (size_t)b * SS * DD + h * 64;
    const short* Kh = K + (size_t)b * SS * DD + h * 64;
    const short* Vh = V + (size_t)b * SS * DD + h * 64;
    short* Oh = O + (size_t)b * SS * DD + h * 64;

    const int qg = qt * 64 + w * 16 + lc;    // this lane's q row (global)
    bf16x8 qa[2];
#pragma unroll
    for (int ks = 0; ks < 2; ++ks)
        qa[ks] = *(const bf16x8*)(Qh + (size_t)qg * DD + ks * 32 + lg * 8);

    f32x4 oaccT[4] = {};
    float l = 0.0f;                          // per-lane partial row-sum

    const int vc = tid & 7, vrp = tid >> 3;  // V staging: ds-chunk, key-pair
    unsigned* Pw = &Pl32[w][0];
    const int kbase_lds = (tid & 0xC0) * 8;  // wave-uniform gload dest

    // ---- prologue: stage tile 0 into buffer 0 ----
    {
        bf16x8 v0 = *(const bf16x8*)(Vh + (size_t)(2 * vrp) * DD + vc * 8);
        bf16x8 v1 = *(const bf16x8*)(Vh + (size_t)(2 * vrp + 1) * DD + vc * 8);
#pragma unroll
        for (int it = 0; it < 2; ++it) {
            int cl = it * 256 + tid;
            int r = cl >> 3;
            int c = (cl & 7) ^ (r & 7);
            gload16(Kh + (size_t)r * DD + c * 8, &Ks[0][it * 2048 + kbase_lds]);
        }
#pragma unroll
        for (int j = 0; j < 8; ++j) {
            int ds = vc * 8 + j;
            unsigned pk = (unsigned)(unsigned short)v0[j] |
                          ((unsigned)(unsigned short)v1[j] << 16);
            Vt32[0][ds * 36 + (vrp ^ (vc << 2))] = pk;
        }
    }
    __syncthreads();
    int cur = 0;

    for (int kt = 0; kt <= qt; ++kt) {
        // ---- stage tile kt+1 into buf^1 (issue early; write V late) ----
        bf16x8 v0n, v1n;
        const bool more = (kt < qt);
        if (more) {
            const int nv0 = (kt + 1) * 64;
            v0n = *(const bf16x8*)(Vh + (size_t)(nv0 + 2 * vrp) * DD + vc * 8);
            v1n = *(const bf16x8*)(Vh + (size_t)(nv0 + 2 * vrp + 1) * DD + vc * 8);
#pragma unroll
            for (int it = 0; it < 2; ++it) {
                int cl = it * 256 + tid;
                int r = cl >> 3;
                int c = (cl & 7) ^ (r & 7);
                gload16(Kh + (size_t)(nv0 + r) * DD + c * 8,
                        &Ks[cur ^ 1][it * 2048 + kbase_lds]);
            }
        }

        // ---- QK^T swapped: s[t] = S^T[key = kv0+t*16+lg*4+rg][q=lc] ----
        f32x4 s[4] = {};
        __builtin_amdgcn_s_setprio(1);
#pragma unroll
        for (int ks = 0; ks < 2; ++ks) {
            int c2 = ks * 4 + lg;
#pragma unroll
            for (int t = 0; t < 4; ++t) {
                int kr = t * 16 + lc;
                bf16x8 kb = *(const bf16x8*)&Ks[cur][kr * 64 + ((c2 ^ (kr & 7)) * 8)];
                s[t] = __builtin_amdgcn_mfma_f32_16x16x32_bf16(kb, qa[ks], s[t], 0, 0, 0);
            }
        }
        __builtin_amdgcn_s_setprio(0);

        // ---- causal mask (diag tile only) ----
        if (kt == qt) {
            const int kv0 = kt * 64;
#pragma unroll
            for (int t = 0; t < 4; ++t)
#pragma unroll
                for (int rg = 0; rg < 4; ++rg)
                    if (kv0 + t * 16 + lg * 4 + rg > qg) s[t][rg] = -1e30f;
        }

        // ---- fixed-m softmax: P = exp2(s); per-lane partial sum ----
#pragma unroll
        for (int t = 0; t < 4; ++t) {
            float p0 = exp2f(s[t][0]);
            float p1 = exp2f(s[t][1]);
            float p2 = exp2f(s[t][2]);
            float p3 = exp2f(s[t][3]);
            l += (p0 + p1) + (p2 + p3);
            uint2 pk;
            pk.x = cvt_pk_bf16(p0, p1);
            pk.y = cvt_pk_bf16(p2, p3);
            *(uint2*)&Pw[lc * 36 + 8 * t + 2 * lg] = pk;
        }

        // ---- PV: O^T[d][q] += V^T[d][k] * P^T[k][q] ----
        __builtin_amdgcn_s_setprio(1);
#pragma unroll
        for (int ks = 0; ks < 2; ++ks) {
            bf16x8 pb = *(const bf16x8*)&Pw[lc * 36 + 16 * ks + 4 * lg];
#pragma unroll
            for (int dt = 0; dt < 4; ++dt) {
                int vr = dt * 16 + lc;
                bf16x8 vb = *(const bf16x8*)&Vt32[cur][vr * 36 +
                                4 * ((ks * 4 + lg) ^ ((vr >> 3) & 7))];
                oaccT[dt] = __builtin_amdgcn_mfma_f32_16x16x32_bf16(vb, pb, oaccT[dt], 0, 0, 0);
            }
        }
        __builtin_amdgcn_s_setprio(0);

        // ---- late V write for tile kt+1 ----
        if (more) {
#pragma unroll
            for (int j = 0; j < 8; ++j) {
                int ds = vc * 8 + j;
                unsigned pk = (unsigned)(unsigned short)v0n[j] |
                              ((unsigned)(unsigned short)v1n[j] << 16);
                Vt32[cur ^ 1][ds * 36 + (vrp ^ (vc << 2))] = pk;
            }
        }
        __syncthreads();   // single barrier per tile
        cur ^= 1;
    }

    // ---- epilogue: finish l across lane groups, write O ----
    l += __shfl_xor(l, 16);
    l += __shfl_xor(l, 32);
    const float inv = 1.0f / l;
#pragma unroll
    for (int dt = 0; dt < 4; ++dt)
#pragma unroll
        for (int rg = 0; rg < 4; ++rg)
            Oh[(size_t)qg * DD + dt * 16 + lg * 4 + rg] = f2bf(oaccT[dt][rg] * inv);
}

// ---------------------------------------------------------------------------
extern "C" void kernel_launch(void* const* d_in, const int* in_sizes, int n_in,
                              void* d_out, int out_size, void* d_ws, size_t ws_size,
                              hipStream_t stream)
{
    const float* x   = (const float*)d_in[0];
    const int*   pos = (const int*)d_in[1];
    const float* Wq  = (const float*)d_in[2];
    const float* Wk  = (const float*)d_in[3];
    const float* Wv  = (const float*)d_in[4];
    const float* Wo  = (const float*)d_in[5];
    float* out = (float*)d_out;

    const size_t T = (size_t)M_TOTAL * DD;
    const size_t WSZ = (size_t)DD * DD;
    short* xb  = (short*)d_ws;
    short* wqb = xb + T;
    short* wkb = wqb + WSZ;
    short* wvb = wkb + WSZ;
    short* wob = wvb + WSZ;
    short* Qb  = wob + WSZ;
    short* Kb  = Qb + T;
    short* Vb  = Kb + T;
    short* AOb = Vb + T;

    // One fused cvt dispatch (8 elems/thread); Wq pre-scaled by 0.125*log2(e).
    const int cvt_blocks = (int)((T + 4 * WSZ) / 2048);
    cvt_all<<<cvt_blocks, 256, 0, stream>>>(x, Wq, Wk, Wv, Wo,
                                            xb, wqb, wkb, wvb, wob,
                                            0.18033688011112042f);

    // QKV fused, n-fastest grid: XCD = bid%8 = n-panel -> W pinned per-XCD L2
    dim3 gqkv(DD / 128, M_TOTAL / 128, 3);
    gemm_nt_mfma<128, 1><<<gqkv, 256, 0, stream>>>(
        xb, wqb, wkb, wvb, Qb, Kb, Vb, M_TOTAL, DD, DD);

    rope_qk<<<(BB * SS * HH * 8) / 256, 256, 0, stream>>>(Qb, Kb, pos);

    // Attention: 1024 blocks, bh in low bits (XCD local), long blocks first
    attn_mfma<<<BB * HH * (SS / 64), 256, 0, stream>>>(Qb, Kb, Vb, AOb);

    // Output projection, n-fastest grid: 512 blocks = 2 blocks/CU
    dim3 go(DD / 64, M_TOTAL / 128, 1);
    gemm_nt_mfma<64, 0><<<go, 256, 0, stream>>>(
        AOb, wob, wob, wob, (void*)out, (void*)out, (void*)out, M_TOTAL, DD, DD);
}